// Round 11
// baseline (289.691 us; speedup 1.0000x reference)
//
#include <hip/hip_runtime.h>

#define BK_SHIFT 8
#define NB_MAX 512
#define CHUNK 4096
#define RSLACK 5120  // per-bucket staging slack; bucket mean 4096, sigma ~64

typedef int i4u __attribute__((ext_vector_type(4), aligned(4)));

// ---------------- Fused weight chain: Y12 = W_in.W_h0.W_h1.W_h2.W_out -----------
// One block, 1024 threads, LDS-staged W, parallel bias reduce (round-4 proven).
// Also zeroes the global bucket counters for the slot-grab scatter.
__global__ __launch_bounds__(1024) void k_chain(const float* __restrict__ W_in,
                                                const float* __restrict__ b_in,
                                                const float* __restrict__ W_hid,
                                                const float* __restrict__ b_hid,
                                                const float* __restrict__ W_out,
                                                float* __restrict__ cvec,
                                                float* __restrict__ Y12,
                                                int* __restrict__ bcnt, int NB) {
  __shared__ float Ws[128][132];
  __shared__ float Bt0[16][132];
  __shared__ float Bt1[16][132];
  __shared__ float part[16][17];  // [k-slice][o]
  int t = threadIdx.x;
  if (t < NB) bcnt[t] = 0;  // counters for k_scatter_grab
  for (int i = t; i < 2048; i += 1024) {
    int o = i >> 7, k = i & 127;
    Bt0[o][k] = (o < 10) ? W_out[k * 10 + o] : 0.f;
  }
  float (*Bc)[132] = Bt0;
  float (*Bn)[132] = Bt1;
  const float* Wp[4] = {W_hid + 2 * 16384, W_hid + 16384, W_hid, W_in};
  const float* bp[4] = {b_hid + 256, b_hid + 128, b_hid, b_in};
#pragma unroll 1
  for (int s = 0; s < 4; s++) {
    const float* W = Wp[s];
    __syncthreads();  // Bc ready; Ws free
    for (int i = t; i < 4096; i += 1024) {
      float4 v = ((const float4*)W)[i];
      int r = i >> 5, c4 = i & 31;
      *(float4*)&Ws[r][c4 * 4] = v;
    }
    if (t < 256) {  // bias partials (reads Bc, unaffected by Ws staging)
      int o = t & 15, sl = t >> 4;
      const float* bias = bp[s];
      float a = 0.f;
#pragma unroll
      for (int kk = 0; kk < 8; kk++) {
        int k = sl * 8 + kk;
        a += bias[k] * Bc[o][k];
      }
      part[sl][o] = a;
    }
    __syncthreads();  // Ws + part ready
    for (int i = t; i < 2048; i += 1024) {
      int o = i & 15, r = i >> 4;
      const float4* wr = (const float4*)&Ws[r][0];
      const float4* br = (const float4*)&Bc[o][0];
      float acc = 0.f;
#pragma unroll 8
      for (int k4 = 0; k4 < 32; k4++) {
        float4 w = wr[k4], bb = br[k4];
        acc += w.x * bb.x + w.y * bb.y + w.z * bb.z + w.w * bb.w;
      }
      Bn[o][r] = acc;
    }
    if (t < 16) {
      float a = 0.f;
#pragma unroll
      for (int sl = 0; sl < 16; sl++) a += part[sl][t];
      cvec[(48 - 16 * s) + t] = a;
    }
    { float (*tmp)[132] = Bc; Bc = Bn; Bn = tmp; }
  }
  __syncthreads();
  for (int i = t; i < 2048; i += 1024) {
    int o = i >> 7, k = i & 127;
    if (o < 12) Y12[k * 12 + o] = Bc[o][k];
  }
}

// ---------------- Slot-grab scatter (512 threads/block) ----------------
// Replaces count+scanB+scatter (measured 41.8us vs their ~59us, round 10).
// staging word = (d & 255) << 24 | src
__global__ __launch_bounds__(512) void k_scatter_grab(const int* __restrict__ src,
                                                      const int* __restrict__ dst,
                                                      int* __restrict__ bcnt,
                                                      unsigned* __restrict__ staging,
                                                      int E, int NB) {
  __shared__ unsigned sval[CHUNK];
  __shared__ int ga0[CHUNK];
  __shared__ int lcnt[NB_MAX];
  __shared__ int gofs[NB_MAX];
  __shared__ int curs[NB_MAX];
  __shared__ int v[512];
  int t = threadIdx.x, b = blockIdx.x;
  for (int i = t; i < NB; i += 512) lcnt[i] = 0;
  __syncthreads();
  int e0 = b * CHUNK, e1 = min(E, e0 + CHUNK);
  int chunkE = e1 - e0;
  if (chunkE == CHUNK) {
    const int4* d4 = (const int4*)(dst + e0);
#pragma unroll 2
    for (int i = t; i < CHUNK / 4; i += 512) {
      int4 w = d4[i];
      atomicAdd(&lcnt[w.x >> BK_SHIFT], 1);
      atomicAdd(&lcnt[w.y >> BK_SHIFT], 1);
      atomicAdd(&lcnt[w.z >> BK_SHIFT], 1);
      atomicAdd(&lcnt[w.w >> BK_SHIFT], 1);
    }
  } else {
    for (int e = e0 + t; e < e1; e += 512) atomicAdd(&lcnt[dst[e] >> BK_SHIFT], 1);
  }
  __syncthreads();
  int base4 = t * 4;
  int a0 = (base4 + 0 < NB) ? lcnt[base4 + 0] : 0;
  int a1 = (base4 + 1 < NB) ? lcnt[base4 + 1] : 0;
  int a2 = (base4 + 2 < NB) ? lcnt[base4 + 2] : 0;
  int a3 = (base4 + 3 < NB) ? lcnt[base4 + 3] : 0;
  // early global slot grab (latency hidden under the scan below)
  int g0 = 0, g1 = 0, g2 = 0, g3 = 0;
  if (a0) g0 = atomicAdd(&bcnt[base4 + 0], a0);
  if (a1) g1 = atomicAdd(&bcnt[base4 + 1], a1);
  if (a2) g2 = atomicAdd(&bcnt[base4 + 2], a2);
  if (a3) g3 = atomicAdd(&bcnt[base4 + 3], a3);
  int s = a0 + a1 + a2 + a3;
  v[t] = s;
  __syncthreads();
  for (int off = 1; off < 512; off <<= 1) {
    int u = (t >= off) ? v[t - off] : 0;
    __syncthreads();
    v[t] += u;
    __syncthreads();
  }
  int run = v[t] - s;  // exclusive
  {
    int aa[4] = {a0, a1, a2, a3};
    int gg[4] = {g0, g1, g2, g3};
#pragma unroll
    for (int i = 0; i < 4; i++) {
      int bk = base4 + i;
      if (bk < NB) {
        gofs[bk] = bk * RSLACK + gg[i] - run;
        curs[bk] = run;
        run += aa[i];
      }
    }
  }
  __syncthreads();
  for (int e = e0 + t; e < e1; e += 512) {
    int d = dst[e];
    int sidx = src[e];
    int bk = d >> BK_SHIFT;
    int slot = atomicAdd(&curs[bk], 1);
    sval[slot] = ((unsigned)(d & 255) << 24) | (unsigned)sidx;
    ga0[slot] = gofs[bk];
  }
  __syncthreads();
  for (int i = t; i < chunkE; i += 512) staging[ga0[i] + i] = sval[i];
}

// Exclusive scan over bucket totals -> bucket base offsets
__global__ __launch_bounds__(1024) void k_bucket_base(const int* __restrict__ bcnt,
                                                      int* __restrict__ bbase, int NB) {
  __shared__ int v[1024];
  int t = threadIdx.x;
  int x = (t < NB) ? bcnt[t] : 0;
  v[t] = x;
  __syncthreads();
  for (int off = 1; off < 1024; off <<= 1) {
    int u = (t >= off) ? v[t - off] : 0;
    __syncthreads();
    v[t] += u;
    __syncthreads();
  }
  if (t < NB) bbase[t] = v[t] - x;
  if (t == 1023) bbase[NB] = v[1023];
}

// Per-bucket counts -> dinv + roff (dense), then in-bucket scatter of col.
// 256 threads (round-4 proven config; the 512-thread variant is the one
// untested suspect in round-10's regression -- this bisects it out).
__global__ __launch_bounds__(256) void k_csr_build(const unsigned* __restrict__ staging,
                                                   const int* __restrict__ bbase,
                                                   int* __restrict__ roff,
                                                   float* __restrict__ dinv,
                                                   int* __restrict__ col,
                                                   int N, int NB, int E) {
  __shared__ int cnt[256];
  __shared__ int sa[256], sb[256];
  __shared__ int cursor[256];
  int t = threadIdx.x, k = blockIdx.x;
  int node0 = k << BK_SHIFT;
  int nNodes = min(256, N - node0);
  int e0 = bbase[k], e1 = bbase[k + 1];
  int ctot = e1 - e0;
  const unsigned* st = staging + (size_t)k * RSLACK;
  cnt[t] = 0;
  __syncthreads();
  for (int i = t; i < ctot; i += 256) atomicAdd(&cnt[st[i] >> 24], 1);
  __syncthreads();
  int* a = sa;
  int* bq = sb;
  a[t] = cnt[t];
  __syncthreads();
  for (int off = 1; off < 256; off <<= 1) {
    bq[t] = (t >= off) ? a[t] + a[t - off] : a[t];
    __syncthreads();
    int* tmp = a; a = bq; bq = tmp;
  }
  {
    int excl = e0 + ((t > 0) ? a[t - 1] : 0);
    cursor[t] = excl;
    if (t < nNodes) {
      roff[node0 + t] = excl;
      dinv[node0 + t] = rsqrtf((float)(cnt[t] + 1));  // +1 = self loop
    }
  }
  if (k == NB - 1 && t == 0) roff[N] = E;
  __syncthreads();
  for (int i = t; i < ctot; i += 256) {
    unsigned p = st[i];
    int slot = atomicAdd(&cursor[p >> 24], 1);
    col[slot] = (int)(p & 0x00FFFFFFu);
  }
}

// ---------------- S0 = dinv * (X @ Y12): LDS-tiled skinny GEMM ----------------

__global__ __launch_bounds__(256) void k_xy(const float* __restrict__ X,
                                            const float* __restrict__ Y12,
                                            const float* __restrict__ dinv,
                                            float* __restrict__ S, int N) {
  __shared__ float Xs[128][132];
  __shared__ float Yt[16][132];  // Yt[o][k], rows 12..15 zero
  int t = threadIdx.x;
  int n0 = blockIdx.x * 128;
  for (int i = t; i < 2048; i += 256) {
    int k = i >> 4, o = i & 15;
    Yt[o][k] = (o < 12) ? Y12[k * 12 + o] : 0.f;
  }
#pragma unroll
  for (int it = 0; it < 16; it++) {
    int idx = t + it * 256;
    int r = idx >> 5;
    int c4 = idx & 31;
    int row = n0 + r;
    float4 v = *(const float4*)&X[(size_t)(row < N ? row : 0) * 128 + c4 * 4];
    *(float4*)&Xs[r][c4 * 4] = v;
  }
  __syncthreads();
  int cp = t & 7;
  int q = t >> 3;
  float acc[4][2];
#pragma unroll
  for (int i = 0; i < 4; i++) { acc[i][0] = 0.f; acc[i][1] = 0.f; }
  const float4* y0r = (const float4*)&Yt[2 * cp][0];
  const float4* y1r = (const float4*)&Yt[2 * cp + 1][0];
#pragma unroll 4
  for (int k4 = 0; k4 < 32; k4++) {
    float4 y0 = y0r[k4];
    float4 y1 = y1r[k4];
#pragma unroll
    for (int i = 0; i < 4; i++) {
      float4 xv = *(const float4*)&Xs[q + 32 * i][k4 * 4];
      acc[i][0] += xv.x * y0.x + xv.y * y0.y + xv.z * y0.z + xv.w * y0.w;
      acc[i][1] += xv.x * y1.x + xv.y * y1.y + xv.z * y1.z + xv.w * y1.w;
    }
  }
#pragma unroll
  for (int i = 0; i < 4; i++) {
    int node = n0 + q + 32 * i;
    if (node < N && cp < 6) {
      float di = dinv[node];
      *(float2*)&S[(size_t)node * 12 + 2 * cp] =
          make_float2(acc[i][0] * di, acc[i][1] * di);
    }
  }
}

// ---------------- Aggregation (round-4 proven: 3N threads, 8-deep MLP) ---------
// g = node*3 + o; every lane live; stride-12 state (4.8MB -- best L2 fit).
__global__ __launch_bounds__(256) void k_agg10(const float4* __restrict__ Sin4,
                                               const int* __restrict__ col,
                                               const int* __restrict__ roff,
                                               const float* __restrict__ dinv,
                                               const float* __restrict__ cvec,
                                               float4* __restrict__ Sout4, int N, int last) {
  int g = blockIdx.x * 256 + threadIdx.x;
  if (g >= N * 3) return;
  int node = g / 3;
  int o = g - node * 3;
  float4 z = Sin4[(size_t)node * 3 + o];
  float ax = z.x, ay = z.y, az = z.z, aw = z.w;
  int j = roff[node], e = roff[node + 1];
  for (; j + 7 < e; j += 8) {
    i4u c0 = *(const i4u*)(col + j);
    i4u c1 = *(const i4u*)(col + j + 4);
    float4 v0 = Sin4[(size_t)c0.x * 3 + o];
    float4 v1 = Sin4[(size_t)c0.y * 3 + o];
    float4 v2 = Sin4[(size_t)c0.z * 3 + o];
    float4 v3 = Sin4[(size_t)c0.w * 3 + o];
    float4 v4 = Sin4[(size_t)c1.x * 3 + o];
    float4 v5 = Sin4[(size_t)c1.y * 3 + o];
    float4 v6 = Sin4[(size_t)c1.z * 3 + o];
    float4 v7 = Sin4[(size_t)c1.w * 3 + o];
    ax += (v0.x + v1.x) + (v2.x + v3.x) + (v4.x + v5.x) + (v6.x + v7.x);
    ay += (v0.y + v1.y) + (v2.y + v3.y) + (v4.y + v5.y) + (v6.y + v7.y);
    az += (v0.z + v1.z) + (v2.z + v3.z) + (v4.z + v5.z) + (v6.z + v7.z);
    aw += (v0.w + v1.w) + (v2.w + v3.w) + (v4.w + v5.w) + (v6.w + v7.w);
  }
  for (; j + 3 < e; j += 4) {
    i4u c = *(const i4u*)(col + j);
    float4 v0 = Sin4[(size_t)c.x * 3 + o];
    float4 v1 = Sin4[(size_t)c.y * 3 + o];
    float4 v2 = Sin4[(size_t)c.z * 3 + o];
    float4 v3 = Sin4[(size_t)c.w * 3 + o];
    ax += (v0.x + v1.x) + (v2.x + v3.x);
    ay += (v0.y + v1.y) + (v2.y + v3.y);
    az += (v0.z + v1.z) + (v2.z + v3.z);
    aw += (v0.w + v1.w) + (v2.w + v3.w);
  }
  for (; j < e; j++) {
    float4 v0 = Sin4[(size_t)col[j] * 3 + o];
    ax += v0.x; ay += v0.y; az += v0.z; aw += v0.w;
  }
  float di = dinv[node];
  float sg = last ? di : di * di;
  float sc = last ? 1.f : di;
  float4 cv = ((const float4*)cvec)[o];
  Sout4[(size_t)node * 3 + o] =
      make_float4(sg * ax + sc * cv.x, sg * ay + sc * cv.y,
                  sg * az + sc * cv.z, sg * aw + sc * cv.w);
}

// ---------------- Pooling + bias (gbounds inlined) ----------------

__global__ __launch_bounds__(128) void k_pool(const float* __restrict__ Z,
                                              const int* __restrict__ batch,
                                              const float* __restrict__ b_out,
                                              float* __restrict__ out, int N, int G) {
  __shared__ float red[8][16];
  __shared__ int bounds[2];
  int g = blockIdx.x;
  int t = threadIdx.x;
  if (t < 2) {
    int target = g + t;
    int lo = 0, hi = N;
    while (lo < hi) {
      int mid = (lo + hi) >> 1;
      if (batch[mid] < target) lo = mid + 1; else hi = mid;
    }
    bounds[t] = lo;
  }
  __syncthreads();
  int s = bounds[0], e = bounds[1];
  int f = t & 15, c = t >> 4;
  float acc = 0.f;
  if (f < 10) {
    for (int n = s + c; n < e; n += 8) acc += Z[(size_t)n * 12 + f];
  }
  red[c][f] = acc;
  __syncthreads();
  if (c == 0 && f < 10) {
    float a = 0.f;
#pragma unroll
    for (int i = 0; i < 8; i++) a += red[i][f];
    out[g * 10 + f] = a / fmaxf((float)(e - s), 1.f) + b_out[f];
  }
}

// ---------------- launch ----------------

extern "C" void kernel_launch(void* const* d_in, const int* in_sizes, int n_in,
                              void* d_out, int out_size, void* d_ws, size_t ws_size,
                              hipStream_t stream) {
  const float* x     = (const float*)d_in[0];
  const int*   eidx  = (const int*)d_in[1];
  const int*   batch = (const int*)d_in[2];
  const float* W_in  = (const float*)d_in[3];
  const float* b_in  = (const float*)d_in[4];
  const float* W_hid = (const float*)d_in[5];
  const float* b_hid = (const float*)d_in[6];
  const float* W_out = (const float*)d_in[7];
  const float* b_out = (const float*)d_in[8];

  const int N = in_sizes[0] / 128;
  const int E = in_sizes[1] / 2;
  const int G = out_size / 10;

  const int* src = eidx;
  const int* dst = eidx + E;

  const int NB = (N + 255) >> BK_SHIFT;
  const int NBLK = (E + CHUNK - 1) / CHUNK;

  char* ws = (char*)d_ws;
  size_t off = 0;
  auto alloc = [&](size_t b) {
    char* p = ws + off;
    off = (off + b + 255) & ~(size_t)255;
    return p;
  };
  unsigned* staging = (unsigned*)alloc((size_t)NB * RSLACK * 4);
  int*   col     = (int*)alloc((size_t)E * 4 + 16);
  int*   bcnt    = (int*)alloc((size_t)NB * 4);
  int*   bbase   = (int*)alloc((size_t)(NB + 1) * 4);
  int*   roff    = (int*)alloc((size_t)(N + 1) * 4);
  float* dinv    = (float*)alloc((size_t)N * 4);
  float* stateA  = (float*)alloc((size_t)N * 12 * 4);
  float* stateB  = (float*)alloc((size_t)N * 12 * 4);
  float* Y12     = (float*)alloc(128 * 12 * 4);
  float* cvec    = (float*)alloc(4 * 16 * 4);
  (void)ws_size; (void)n_in;

  // Weight chain (also zeroes bcnt for the slot-grab scatter)
  k_chain<<<1, 1024, 0, stream>>>(W_in, b_in, W_hid, b_hid, W_out, cvec, Y12, bcnt, NB);

  // CSR build: slot-grab scatter (512 thr) -> bucket-base scan -> per-bucket build
  k_scatter_grab<<<NBLK, 512, 0, stream>>>(src, dst, bcnt, staging, E, NB);
  k_bucket_base<<<1, 1024, 0, stream>>>(bcnt, bbase, NB);
  k_csr_build<<<NB, 256, 0, stream>>>(staging, bbase, roff, dinv, col, N, NB, E);

  // S0 = dinv * (X @ Y)
  k_xy<<<(N + 127) / 128, 256, 0, stream>>>(x, Y12, dinv, stateA, N);

  // 4 gather passes (round-4 proven mapping; stride-12 state)
  float* zi = stateA;
  float* zo = stateB;
  int aggBlocks = (N * 3 + 255) / 256;
  for (int l = 0; l < 4; l++) {
    k_agg10<<<aggBlocks, 256, 0, stream>>>((const float4*)zi, col, roff, dinv,
                                           cvec + 16 * l, (float4*)zo, N, (l == 3) ? 1 : 0);
    float* t = zi; zi = zo; zo = t;
  }

  k_pool<<<G, 128, 0, stream>>>(zi, batch, b_out, (float*)d_out, N, G);
}

// Round 12
// 265.322 us; speedup vs baseline: 1.0918x; 1.0918x over previous
//
#include <hip/hip_runtime.h>

#define BK_SHIFT 8
#define NB_MAX 512
#define CHUNK 4096

typedef int i4u __attribute__((ext_vector_type(4), aligned(4)));

// ---------------- Pass A: per-block bucket histogram (bucket = dst >> 8) -------
__global__ __launch_bounds__(256) void k_bucket_count(const int* __restrict__ dst,
                                                      int* __restrict__ blkcnt,
                                                      int E, int NB, int NBLK) {
  __shared__ int cnt[NB_MAX];
  int t = threadIdx.x, b = blockIdx.x;
  for (int i = t; i < NB; i += 256) cnt[i] = 0;
  __syncthreads();
  int e0 = b * CHUNK, e1 = min(E, e0 + CHUNK);
  if (e1 - e0 == CHUNK) {
    const int4* d4 = (const int4*)(dst + e0);
#pragma unroll 2
    for (int i = t; i < CHUNK / 4; i += 256) {
      int4 v = d4[i];
      atomicAdd(&cnt[v.x >> BK_SHIFT], 1);
      atomicAdd(&cnt[v.y >> BK_SHIFT], 1);
      atomicAdd(&cnt[v.z >> BK_SHIFT], 1);
      atomicAdd(&cnt[v.w >> BK_SHIFT], 1);
    }
  } else {
    for (int e = e0 + t; e < e1; e += 256) atomicAdd(&cnt[dst[e] >> BK_SHIFT], 1);
  }
  __syncthreads();
  for (int i = t; i < NB; i += 256) blkcnt[(size_t)i * NBLK + b] = cnt[i];
}

// Pass B: per-bucket exclusive scan across blocks (in place), bucket totals out.
__global__ __launch_bounds__(512) void k_bucket_scanB(int* __restrict__ blkcnt,
                                                      int* __restrict__ btot, int NBLK) {
  __shared__ int v[512];
  int t = threadIdx.x, k = blockIdx.x;
  int x = (t < NBLK) ? blkcnt[(size_t)k * NBLK + t] : 0;
  v[t] = x;
  __syncthreads();
  for (int off = 1; off < 512; off <<= 1) {
    int u = (t >= off) ? v[t - off] : 0;
    __syncthreads();
    v[t] += u;
    __syncthreads();
  }
  if (t < NBLK) blkcnt[(size_t)k * NBLK + t] = v[t] - x;  // exclusive
  if (t == 511) btot[k] = v[511];
}

// Pass B2: exclusive scan over bucket totals -> bucket base offsets
__global__ __launch_bounds__(1024) void k_bucket_base(const int* __restrict__ btot,
                                                      int* __restrict__ bbase, int NB) {
  __shared__ int v[1024];
  int t = threadIdx.x;
  int x = (t < NB) ? btot[t] : 0;
  v[t] = x;
  __syncthreads();
  for (int off = 1; off < 1024; off <<= 1) {
    int u = (t >= off) ? v[t - off] : 0;
    __syncthreads();
    v[t] += u;
    __syncthreads();
  }
  if (t < NB) bbase[t] = v[t] - x;
  if (t == 1023) bbase[NB] = v[1023];
}

// ---------------- Merged scatter + xy (independent work, one dispatch) ----------
// Blocks [0, NBLK): the R4 LDS-sort scatter (latency-bound, ~46us, <6% HBM).
// Blocks [NBLK, NBLK+XYB): S_raw = X @ Y12 (HBM-BW-bound, reads 51.2MB of X),
// UNSCALED -- the dinv scaling moved to k_csr_build, removing the dependency
// that forced xy to run serially after the CSR build. The BW-bound xy work
// hides under the scatter's idle memory system. Union LDS = 76KB -> 2 blocks/CU
// for both paths (xy was already 76KB; scatter loses nothing at 391 blocks).
// staging word = (d & 255) << 24 | src
__global__ __launch_bounds__(256) void k_scatter_xy(const int* __restrict__ src,
                                                    const int* __restrict__ dst,
                                                    const int* __restrict__ blkoff,
                                                    const int* __restrict__ bbase,
                                                    unsigned* __restrict__ staging,
                                                    int E, int NB, int NBLK,
                                                    const float* __restrict__ X,
                                                    const float* __restrict__ Y12,
                                                    float* __restrict__ S, int N) {
  __shared__ float smem[19008];  // 76032 B: xy = Xs[128][132]+Yt[16][132]; scatter = 39936 B
  int t = threadIdx.x, b = blockIdx.x;

  if (b < NBLK) {
    // ---- scatter path (R4 k_bucket_scatter, LDS carved from smem) ----
    int* si = (int*)smem;
    unsigned* sval = (unsigned*)si;   // [0, 4096)
    int* ga0  = si + 4096;            // [4096, 8192)
    int* lcnt = si + 8192;            // [8192, 8704)
    int* gofs = si + 8704;
    int* curs = si + 9216;
    int* v    = si + 9728;            // [9728, 9984)
    for (int i = t; i < NB; i += 256) lcnt[i] = 0;
    __syncthreads();
    int e0 = b * CHUNK, e1 = min(E, e0 + CHUNK);
    int chunkE = e1 - e0;
    if (chunkE == CHUNK) {
      const int4* d4 = (const int4*)(dst + e0);
#pragma unroll 2
      for (int i = t; i < CHUNK / 4; i += 256) {
        int4 w = d4[i];
        atomicAdd(&lcnt[w.x >> BK_SHIFT], 1);
        atomicAdd(&lcnt[w.y >> BK_SHIFT], 1);
        atomicAdd(&lcnt[w.z >> BK_SHIFT], 1);
        atomicAdd(&lcnt[w.w >> BK_SHIFT], 1);
      }
    } else {
      for (int e = e0 + t; e < e1; e += 256) atomicAdd(&lcnt[dst[e] >> BK_SHIFT], 1);
    }
    __syncthreads();
    int base4 = t * 4;
    int a0 = (base4 + 0 < NB) ? lcnt[base4 + 0] : 0;
    int a1 = (base4 + 1 < NB) ? lcnt[base4 + 1] : 0;
    int a2 = (base4 + 2 < NB) ? lcnt[base4 + 2] : 0;
    int a3 = (base4 + 3 < NB) ? lcnt[base4 + 3] : 0;
    int s = a0 + a1 + a2 + a3;
    v[t] = s;
    __syncthreads();
    for (int off = 1; off < 256; off <<= 1) {
      int u = (t >= off) ? v[t - off] : 0;
      __syncthreads();
      v[t] += u;
      __syncthreads();
    }
    int run = v[t] - s;  // exclusive
    {
      int aa[4] = {a0, a1, a2, a3};
#pragma unroll
      for (int i = 0; i < 4; i++) {
        int bk = base4 + i;
        if (bk < NB) {
          gofs[bk] = bbase[bk] + blkoff[(size_t)bk * NBLK + b] - run;
          curs[bk] = run;
          run += aa[i];
        }
      }
    }
    __syncthreads();
    for (int e = e0 + t; e < e1; e += 256) {
      int d = dst[e];
      int sidx = src[e];
      int bk = d >> BK_SHIFT;
      int slot = atomicAdd(&curs[bk], 1);
      sval[slot] = ((unsigned)(d & 255) << 24) | (unsigned)sidx;
      ga0[slot] = gofs[bk];
    }
    __syncthreads();
    for (int i = t; i < chunkE; i += 256) staging[ga0[i] + i] = sval[i];
    return;
  }

  // ---- xy path: S_raw = X @ Y12 (unscaled) ----
  float (*Xs)[132] = (float(*)[132])smem;            // 128 x 132
  float (*Yt)[132] = (float(*)[132])(smem + 16896);  // 16 x 132
  int n0 = (b - NBLK) * 128;
  for (int i = t; i < 2048; i += 256) {
    int k = i >> 4, o = i & 15;
    Yt[o][k] = (o < 12) ? Y12[k * 12 + o] : 0.f;
  }
#pragma unroll
  for (int it = 0; it < 16; it++) {
    int idx = t + it * 256;
    int r = idx >> 5;
    int c4 = idx & 31;
    int row = n0 + r;
    float4 vv = *(const float4*)&X[(size_t)(row < N ? row : 0) * 128 + c4 * 4];
    *(float4*)&Xs[r][c4 * 4] = vv;
  }
  __syncthreads();
  int cp = t & 7;
  int q = t >> 3;
  float acc[4][2];
#pragma unroll
  for (int i = 0; i < 4; i++) { acc[i][0] = 0.f; acc[i][1] = 0.f; }
  const float4* y0r = (const float4*)&Yt[2 * cp][0];
  const float4* y1r = (const float4*)&Yt[2 * cp + 1][0];
#pragma unroll 4
  for (int k4 = 0; k4 < 32; k4++) {
    float4 y0 = y0r[k4];
    float4 y1 = y1r[k4];
#pragma unroll
    for (int i = 0; i < 4; i++) {
      float4 xv = *(const float4*)&Xs[q + 32 * i][k4 * 4];
      acc[i][0] += xv.x * y0.x + xv.y * y0.y + xv.z * y0.z + xv.w * y0.w;
      acc[i][1] += xv.x * y1.x + xv.y * y1.y + xv.z * y1.z + xv.w * y1.w;
    }
  }
#pragma unroll
  for (int i = 0; i < 4; i++) {
    int node = n0 + q + 32 * i;
    if (node < N && cp < 6) {
      *(float2*)&S[(size_t)node * 12 + 2 * cp] = make_float2(acc[i][0], acc[i][1]);
    }
  }
}

// Pass D: per-bucket counts -> dinv + roff, in-bucket scatter of col, and the
// deferred dinv-scaling of this bucket's 256 contiguous S rows (768 float4s,
// coalesced -- ~1us total across the grid).
__global__ __launch_bounds__(256) void k_csr_build(const unsigned* __restrict__ staging,
                                                   const int* __restrict__ bbase,
                                                   int* __restrict__ roff,
                                                   float* __restrict__ dinv,
                                                   int* __restrict__ col,
                                                   float* __restrict__ S,
                                                   int N, int NB, int E) {
  __shared__ int cnt[256];
  __shared__ int sa[256], sb[256];
  __shared__ int cursor[256];
  __shared__ float dsh[256];
  int t = threadIdx.x, k = blockIdx.x;
  int node0 = k << BK_SHIFT;
  int nNodes = min(256, N - node0);
  int e0 = bbase[k], e1 = bbase[k + 1];
  cnt[t] = 0;
  __syncthreads();
  for (int e = e0 + t; e < e1; e += 256) atomicAdd(&cnt[staging[e] >> 24], 1);
  __syncthreads();
  int* a = sa;
  int* bq = sb;
  a[t] = cnt[t];
  __syncthreads();
  for (int off = 1; off < 256; off <<= 1) {
    bq[t] = (t >= off) ? a[t] + a[t - off] : a[t];
    __syncthreads();
    int* tmp = a; a = bq; bq = tmp;
  }
  {
    int excl = e0 + ((t > 0) ? a[t - 1] : 0);
    cursor[t] = excl;
    float di = rsqrtf((float)(cnt[t] + 1));  // +1 = self loop
    dsh[t] = di;
    if (t < nNodes) {
      roff[node0 + t] = excl;
      dinv[node0 + t] = di;
    }
  }
  if (k == NB - 1 && t == 0) roff[N] = E;
  __syncthreads();
  for (int e = e0 + t; e < e1; e += 256) {
    unsigned p = staging[e];
    int slot = atomicAdd(&cursor[p >> 24], 1);
    col[slot] = (int)(p & 0x00FFFFFFu);
  }
  // deferred S *= dinv for rows [node0, node0+nNodes): 12 floats = 3 float4/row
  float4* Sp4 = (float4*)(S + (size_t)node0 * 12);
  int lim = nNodes * 3;
  for (int i = t; i < lim; i += 256) {
    float4 vv = Sp4[i];
    float d = dsh[i / 3];
    vv.x *= d; vv.y *= d; vv.z *= d; vv.w *= d;
    Sp4[i] = vv;
  }
}

// ---------------- Fused weight chain: Y12 = W_in.W_h0.W_h1.W_h2.W_out -----------
// One block, 1024 threads, LDS-staged W, parallel bias reduce (round-4 proven).
__global__ __launch_bounds__(1024) void k_chain(const float* __restrict__ W_in,
                                                const float* __restrict__ b_in,
                                                const float* __restrict__ W_hid,
                                                const float* __restrict__ b_hid,
                                                const float* __restrict__ W_out,
                                                float* __restrict__ cvec,
                                                float* __restrict__ Y12) {
  __shared__ float Ws[128][132];
  __shared__ float Bt0[16][132];
  __shared__ float Bt1[16][132];
  __shared__ float part[16][17];  // [k-slice][o]
  int t = threadIdx.x;
  for (int i = t; i < 2048; i += 1024) {
    int o = i >> 7, k = i & 127;
    Bt0[o][k] = (o < 10) ? W_out[k * 10 + o] : 0.f;
  }
  float (*Bc)[132] = Bt0;
  float (*Bn)[132] = Bt1;
  const float* Wp[4] = {W_hid + 2 * 16384, W_hid + 16384, W_hid, W_in};
  const float* bp[4] = {b_hid + 256, b_hid + 128, b_hid, b_in};
#pragma unroll 1
  for (int s = 0; s < 4; s++) {
    const float* W = Wp[s];
    __syncthreads();  // Bc ready; Ws free
    for (int i = t; i < 4096; i += 1024) {
      float4 v = ((const float4*)W)[i];
      int r = i >> 5, c4 = i & 31;
      *(float4*)&Ws[r][c4 * 4] = v;
    }
    if (t < 256) {  // bias partials (reads Bc, unaffected by Ws staging)
      int o = t & 15, sl = t >> 4;
      const float* bias = bp[s];
      float a = 0.f;
#pragma unroll
      for (int kk = 0; kk < 8; kk++) {
        int k = sl * 8 + kk;
        a += bias[k] * Bc[o][k];
      }
      part[sl][o] = a;
    }
    __syncthreads();  // Ws + part ready
    for (int i = t; i < 2048; i += 1024) {
      int o = i & 15, r = i >> 4;
      const float4* wr = (const float4*)&Ws[r][0];
      const float4* br = (const float4*)&Bc[o][0];
      float acc = 0.f;
#pragma unroll 8
      for (int k4 = 0; k4 < 32; k4++) {
        float4 w = wr[k4], bb = br[k4];
        acc += w.x * bb.x + w.y * bb.y + w.z * bb.z + w.w * bb.w;
      }
      Bn[o][r] = acc;
    }
    if (t < 16) {
      float a = 0.f;
#pragma unroll
      for (int sl = 0; sl < 16; sl++) a += part[sl][t];
      cvec[(48 - 16 * s) + t] = a;
    }
    { float (*tmp)[132] = Bc; Bc = Bn; Bn = tmp; }
  }
  __syncthreads();
  for (int i = t; i < 2048; i += 1024) {
    int o = i >> 7, k = i & 127;
    if (o < 12) Y12[k * 12 + o] = Bc[o][k];
  }
}

// ---------------- Aggregation (round-4 proven: 3N threads, 8-deep MLP) ---------
// g = node*3 + o; every lane live; stride-12 state (4.8MB -- best L2 fit).
__global__ __launch_bounds__(256) void k_agg10(const float4* __restrict__ Sin4,
                                               const int* __restrict__ col,
                                               const int* __restrict__ roff,
                                               const float* __restrict__ dinv,
                                               const float* __restrict__ cvec,
                                               float4* __restrict__ Sout4, int N, int last) {
  int g = blockIdx.x * 256 + threadIdx.x;
  if (g >= N * 3) return;
  int node = g / 3;
  int o = g - node * 3;
  float4 z = Sin4[(size_t)node * 3 + o];
  float ax = z.x, ay = z.y, az = z.z, aw = z.w;
  int j = roff[node], e = roff[node + 1];
  for (; j + 7 < e; j += 8) {
    i4u c0 = *(const i4u*)(col + j);
    i4u c1 = *(const i4u*)(col + j + 4);
    float4 v0 = Sin4[(size_t)c0.x * 3 + o];
    float4 v1 = Sin4[(size_t)c0.y * 3 + o];
    float4 v2 = Sin4[(size_t)c0.z * 3 + o];
    float4 v3 = Sin4[(size_t)c0.w * 3 + o];
    float4 v4 = Sin4[(size_t)c1.x * 3 + o];
    float4 v5 = Sin4[(size_t)c1.y * 3 + o];
    float4 v6 = Sin4[(size_t)c1.z * 3 + o];
    float4 v7 = Sin4[(size_t)c1.w * 3 + o];
    ax += (v0.x + v1.x) + (v2.x + v3.x) + (v4.x + v5.x) + (v6.x + v7.x);
    ay += (v0.y + v1.y) + (v2.y + v3.y) + (v4.y + v5.y) + (v6.y + v7.y);
    az += (v0.z + v1.z) + (v2.z + v3.z) + (v4.z + v5.z) + (v6.z + v7.z);
    aw += (v0.w + v1.w) + (v2.w + v3.w) + (v4.w + v5.w) + (v6.w + v7.w);
  }
  for (; j + 3 < e; j += 4) {
    i4u c = *(const i4u*)(col + j);
    float4 v0 = Sin4[(size_t)c.x * 3 + o];
    float4 v1 = Sin4[(size_t)c.y * 3 + o];
    float4 v2 = Sin4[(size_t)c.z * 3 + o];
    float4 v3 = Sin4[(size_t)c.w * 3 + o];
    ax += (v0.x + v1.x) + (v2.x + v3.x);
    ay += (v0.y + v1.y) + (v2.y + v3.y);
    az += (v0.z + v1.z) + (v2.z + v3.z);
    aw += (v0.w + v1.w) + (v2.w + v3.w);
  }
  for (; j < e; j++) {
    float4 v0 = Sin4[(size_t)col[j] * 3 + o];
    ax += v0.x; ay += v0.y; az += v0.z; aw += v0.w;
  }
  float di = dinv[node];
  float sg = last ? di : di * di;
  float sc = last ? 1.f : di;
  float4 cv = ((const float4*)cvec)[o];
  Sout4[(size_t)node * 3 + o] =
      make_float4(sg * ax + sc * cv.x, sg * ay + sc * cv.y,
                  sg * az + sc * cv.z, sg * aw + sc * cv.w);
}

// ---------------- Pooling + bias (gbounds inlined) ----------------

__global__ __launch_bounds__(128) void k_pool(const float* __restrict__ Z,
                                              const int* __restrict__ batch,
                                              const float* __restrict__ b_out,
                                              float* __restrict__ out, int N, int G) {
  __shared__ float red[8][16];
  __shared__ int bounds[2];
  int g = blockIdx.x;
  int t = threadIdx.x;
  if (t < 2) {
    int target = g + t;
    int lo = 0, hi = N;
    while (lo < hi) {
      int mid = (lo + hi) >> 1;
      if (batch[mid] < target) lo = mid + 1; else hi = mid;
    }
    bounds[t] = lo;
  }
  __syncthreads();
  int s = bounds[0], e = bounds[1];
  int f = t & 15, c = t >> 4;
  float acc = 0.f;
  if (f < 10) {
    for (int n = s + c; n < e; n += 8) acc += Z[(size_t)n * 12 + f];
  }
  red[c][f] = acc;
  __syncthreads();
  if (c == 0 && f < 10) {
    float a = 0.f;
#pragma unroll
    for (int i = 0; i < 8; i++) a += red[i][f];
    out[g * 10 + f] = a / fmaxf((float)(e - s), 1.f) + b_out[f];
  }
}

// ---------------- launch ----------------

extern "C" void kernel_launch(void* const* d_in, const int* in_sizes, int n_in,
                              void* d_out, int out_size, void* d_ws, size_t ws_size,
                              hipStream_t stream) {
  const float* x     = (const float*)d_in[0];
  const int*   eidx  = (const int*)d_in[1];
  const int*   batch = (const int*)d_in[2];
  const float* W_in  = (const float*)d_in[3];
  const float* b_in  = (const float*)d_in[4];
  const float* W_hid = (const float*)d_in[5];
  const float* b_hid = (const float*)d_in[6];
  const float* W_out = (const float*)d_in[7];
  const float* b_out = (const float*)d_in[8];

  const int N = in_sizes[0] / 128;
  const int E = in_sizes[1] / 2;
  const int G = out_size / 10;

  const int* src = eidx;
  const int* dst = eidx + E;

  const int NB = (N + 255) >> BK_SHIFT;
  const int NBLK = (E + CHUNK - 1) / CHUNK;
  const int XYB = (N + 127) / 128;

  char* ws = (char*)d_ws;
  size_t off = 0;
  auto alloc = [&](size_t b) {
    char* p = ws + off;
    off = (off + b + 255) & ~(size_t)255;
    return p;
  };
  unsigned* staging = (unsigned*)alloc((size_t)E * 4);
  int*   col     = (int*)alloc((size_t)E * 4 + 16);
  int*   blkcnt  = (int*)alloc((size_t)NB * NBLK * 4);
  int*   btot    = (int*)alloc((size_t)NB * 4);
  int*   bbase   = (int*)alloc((size_t)(NB + 1) * 4);
  int*   roff    = (int*)alloc((size_t)(N + 1) * 4);
  float* dinv    = (float*)alloc((size_t)N * 4);
  float* stateA  = (float*)alloc((size_t)N * 12 * 4);
  float* stateB  = (float*)alloc((size_t)N * 12 * 4);
  float* Y12     = (float*)alloc(128 * 12 * 4);
  float* cvec    = (float*)alloc(4 * 16 * 4);
  (void)ws_size; (void)n_in;

  // Weight chain (single kernel, 1024 thr, parallel bias reduce)
  k_chain<<<1, 1024, 0, stream>>>(W_in, b_in, W_hid, b_hid, W_out, cvec, Y12);

  // Bucketed CSR build; xy (unscaled) merged into the scatter dispatch
  k_bucket_count<<<NBLK, 256, 0, stream>>>(dst, blkcnt, E, NB, NBLK);
  k_bucket_scanB<<<NB, 512, 0, stream>>>(blkcnt, btot, NBLK);
  k_bucket_base<<<1, 1024, 0, stream>>>(btot, bbase, NB);
  k_scatter_xy<<<NBLK + XYB, 256, 0, stream>>>(src, dst, blkcnt, bbase, staging,
                                               E, NB, NBLK, x, Y12, stateA, N);
  k_csr_build<<<NB, 256, 0, stream>>>(staging, bbase, roff, dinv, col, stateA, N, NB, E);

  // 4 gather passes (round-4 proven mapping; stride-12 state)
  float* zi = stateA;
  float* zo = stateB;
  int aggBlocks = (N * 3 + 255) / 256;
  for (int l = 0; l < 4; l++) {
    k_agg10<<<aggBlocks, 256, 0, stream>>>((const float4*)zi, col, roff, dinv,
                                           cvec + 16 * l, (float4*)zo, N, (l == 3) ? 1 : 0);
    float* t = zi; zi = zo; zo = t;
  }

  k_pool<<<G, 128, 0, stream>>>(zi, batch, b_out, (float*)d_out, N, G);
}

// Round 13
// 262.575 us; speedup vs baseline: 1.1033x; 1.0105x over previous
//
#include <hip/hip_runtime.h>

#define BK_SHIFT 8
#define NB_MAX 512
#define CHUNK 4096

typedef int i4u __attribute__((ext_vector_type(4), aligned(4)));

// ---------------- Pass A: per-block bucket histogram (bucket = dst >> 8) -------
__global__ __launch_bounds__(256) void k_bucket_count(const int* __restrict__ dst,
                                                      int* __restrict__ blkcnt,
                                                      int E, int NB, int NBLK) {
  __shared__ int cnt[NB_MAX];
  int t = threadIdx.x, b = blockIdx.x;
  for (int i = t; i < NB; i += 256) cnt[i] = 0;
  __syncthreads();
  int e0 = b * CHUNK, e1 = min(E, e0 + CHUNK);
  if (e1 - e0 == CHUNK) {
    const int4* d4 = (const int4*)(dst + e0);
#pragma unroll 2
    for (int i = t; i < CHUNK / 4; i += 256) {
      int4 v = d4[i];
      atomicAdd(&cnt[v.x >> BK_SHIFT], 1);
      atomicAdd(&cnt[v.y >> BK_SHIFT], 1);
      atomicAdd(&cnt[v.z >> BK_SHIFT], 1);
      atomicAdd(&cnt[v.w >> BK_SHIFT], 1);
    }
  } else {
    for (int e = e0 + t; e < e1; e += 256) atomicAdd(&cnt[dst[e] >> BK_SHIFT], 1);
  }
  __syncthreads();
  for (int i = t; i < NB; i += 256) blkcnt[(size_t)i * NBLK + b] = cnt[i];
}

// Pass B: per-bucket exclusive scan across blocks (in place), bucket totals out.
__global__ __launch_bounds__(512) void k_bucket_scanB(int* __restrict__ blkcnt,
                                                      int* __restrict__ btot, int NBLK) {
  __shared__ int v[512];
  int t = threadIdx.x, k = blockIdx.x;
  int x = (t < NBLK) ? blkcnt[(size_t)k * NBLK + t] : 0;
  v[t] = x;
  __syncthreads();
  for (int off = 1; off < 512; off <<= 1) {
    int u = (t >= off) ? v[t - off] : 0;
    __syncthreads();
    v[t] += u;
    __syncthreads();
  }
  if (t < NBLK) blkcnt[(size_t)k * NBLK + t] = v[t] - x;  // exclusive
  if (t == 511) btot[k] = v[511];
}

// Pass B2: exclusive scan over bucket totals -> bucket base offsets
__global__ __launch_bounds__(1024) void k_bucket_base(const int* __restrict__ btot,
                                                      int* __restrict__ bbase, int NB) {
  __shared__ int v[1024];
  int t = threadIdx.x;
  int x = (t < NB) ? btot[t] : 0;
  v[t] = x;
  __syncthreads();
  for (int off = 1; off < 1024; off <<= 1) {
    int u = (t >= off) ? v[t - off] : 0;
    __syncthreads();
    v[t] += u;
    __syncthreads();
  }
  if (t < NB) bbase[t] = v[t] - x;
  if (t == 1023) bbase[NB] = v[1023];
}

// ---------------- Merged scatter + xy (R12 proven, byte-identical) ----------
// staging word = (d & 255) << 24 | src
__global__ __launch_bounds__(256) void k_scatter_xy(const int* __restrict__ src,
                                                    const int* __restrict__ dst,
                                                    const int* __restrict__ blkoff,
                                                    const int* __restrict__ bbase,
                                                    unsigned* __restrict__ staging,
                                                    int E, int NB, int NBLK,
                                                    const float* __restrict__ X,
                                                    const float* __restrict__ Y12,
                                                    float* __restrict__ S, int N) {
  __shared__ float smem[19008];  // 76032 B: xy = Xs[128][132]+Yt[16][132]; scatter = 39936 B
  int t = threadIdx.x, b = blockIdx.x;

  if (b < NBLK) {
    // ---- scatter path (R4 k_bucket_scatter, LDS carved from smem) ----
    int* si = (int*)smem;
    unsigned* sval = (unsigned*)si;   // [0, 4096)
    int* ga0  = si + 4096;            // [4096, 8192)
    int* lcnt = si + 8192;            // [8192, 8704)
    int* gofs = si + 8704;
    int* curs = si + 9216;
    int* v    = si + 9728;            // [9728, 9984)
    for (int i = t; i < NB; i += 256) lcnt[i] = 0;
    __syncthreads();
    int e0 = b * CHUNK, e1 = min(E, e0 + CHUNK);
    int chunkE = e1 - e0;
    if (chunkE == CHUNK) {
      const int4* d4 = (const int4*)(dst + e0);
#pragma unroll 2
      for (int i = t; i < CHUNK / 4; i += 256) {
        int4 w = d4[i];
        atomicAdd(&lcnt[w.x >> BK_SHIFT], 1);
        atomicAdd(&lcnt[w.y >> BK_SHIFT], 1);
        atomicAdd(&lcnt[w.z >> BK_SHIFT], 1);
        atomicAdd(&lcnt[w.w >> BK_SHIFT], 1);
      }
    } else {
      for (int e = e0 + t; e < e1; e += 256) atomicAdd(&lcnt[dst[e] >> BK_SHIFT], 1);
    }
    __syncthreads();
    int base4 = t * 4;
    int a0 = (base4 + 0 < NB) ? lcnt[base4 + 0] : 0;
    int a1 = (base4 + 1 < NB) ? lcnt[base4 + 1] : 0;
    int a2 = (base4 + 2 < NB) ? lcnt[base4 + 2] : 0;
    int a3 = (base4 + 3 < NB) ? lcnt[base4 + 3] : 0;
    int s = a0 + a1 + a2 + a3;
    v[t] = s;
    __syncthreads();
    for (int off = 1; off < 256; off <<= 1) {
      int u = (t >= off) ? v[t - off] : 0;
      __syncthreads();
      v[t] += u;
      __syncthreads();
    }
    int run = v[t] - s;  // exclusive
    {
      int aa[4] = {a0, a1, a2, a3};
#pragma unroll
      for (int i = 0; i < 4; i++) {
        int bk = base4 + i;
        if (bk < NB) {
          gofs[bk] = bbase[bk] + blkoff[(size_t)bk * NBLK + b] - run;
          curs[bk] = run;
          run += aa[i];
        }
      }
    }
    __syncthreads();
    for (int e = e0 + t; e < e1; e += 256) {
      int d = dst[e];
      int sidx = src[e];
      int bk = d >> BK_SHIFT;
      int slot = atomicAdd(&curs[bk], 1);
      sval[slot] = ((unsigned)(d & 255) << 24) | (unsigned)sidx;
      ga0[slot] = gofs[bk];
    }
    __syncthreads();
    for (int i = t; i < chunkE; i += 256) staging[ga0[i] + i] = sval[i];
    return;
  }

  // ---- xy path: S_raw = X @ Y12 (unscaled; dinv applied in k_csr_build) ----
  float (*Xs)[132] = (float(*)[132])smem;            // 128 x 132
  float (*Yt)[132] = (float(*)[132])(smem + 16896);  // 16 x 132
  int n0 = (b - NBLK) * 128;
  for (int i = t; i < 2048; i += 256) {
    int k = i >> 4, o = i & 15;
    Yt[o][k] = (o < 12) ? Y12[k * 12 + o] : 0.f;
  }
#pragma unroll
  for (int it = 0; it < 16; it++) {
    int idx = t + it * 256;
    int r = idx >> 5;
    int c4 = idx & 31;
    int row = n0 + r;
    float4 vv = *(const float4*)&X[(size_t)(row < N ? row : 0) * 128 + c4 * 4];
    *(float4*)&Xs[r][c4 * 4] = vv;
  }
  __syncthreads();
  int cp = t & 7;
  int q = t >> 3;
  float acc[4][2];
#pragma unroll
  for (int i = 0; i < 4; i++) { acc[i][0] = 0.f; acc[i][1] = 0.f; }
  const float4* y0r = (const float4*)&Yt[2 * cp][0];
  const float4* y1r = (const float4*)&Yt[2 * cp + 1][0];
#pragma unroll 4
  for (int k4 = 0; k4 < 32; k4++) {
    float4 y0 = y0r[k4];
    float4 y1 = y1r[k4];
#pragma unroll
    for (int i = 0; i < 4; i++) {
      float4 xv = *(const float4*)&Xs[q + 32 * i][k4 * 4];
      acc[i][0] += xv.x * y0.x + xv.y * y0.y + xv.z * y0.z + xv.w * y0.w;
      acc[i][1] += xv.x * y1.x + xv.y * y1.y + xv.z * y1.z + xv.w * y1.w;
    }
  }
#pragma unroll
  for (int i = 0; i < 4; i++) {
    int node = n0 + q + 32 * i;
    if (node < N && cp < 6) {
      *(float2*)&S[(size_t)node * 12 + 2 * cp] = make_float2(acc[i][0], acc[i][1]);
    }
  }
}

// Pass D: counts -> dinv + roff, in-bucket col scatter, deferred S *= dinv.
__global__ __launch_bounds__(256) void k_csr_build(const unsigned* __restrict__ staging,
                                                   const int* __restrict__ bbase,
                                                   int* __restrict__ roff,
                                                   float* __restrict__ dinv,
                                                   int* __restrict__ col,
                                                   float* __restrict__ S,
                                                   int N, int NB, int E) {
  __shared__ int cnt[256];
  __shared__ int sa[256], sb[256];
  __shared__ int cursor[256];
  __shared__ float dsh[256];
  int t = threadIdx.x, k = blockIdx.x;
  int node0 = k << BK_SHIFT;
  int nNodes = min(256, N - node0);
  int e0 = bbase[k], e1 = bbase[k + 1];
  cnt[t] = 0;
  __syncthreads();
  for (int e = e0 + t; e < e1; e += 256) atomicAdd(&cnt[staging[e] >> 24], 1);
  __syncthreads();
  int* a = sa;
  int* bq = sb;
  a[t] = cnt[t];
  __syncthreads();
  for (int off = 1; off < 256; off <<= 1) {
    bq[t] = (t >= off) ? a[t] + a[t - off] : a[t];
    __syncthreads();
    int* tmp = a; a = bq; bq = tmp;
  }
  {
    int excl = e0 + ((t > 0) ? a[t - 1] : 0);
    cursor[t] = excl;
    float di = rsqrtf((float)(cnt[t] + 1));  // +1 = self loop
    dsh[t] = di;
    if (t < nNodes) {
      roff[node0 + t] = excl;
      dinv[node0 + t] = di;
    }
  }
  if (k == NB - 1 && t == 0) roff[N] = E;
  __syncthreads();
  for (int e = e0 + t; e < e1; e += 256) {
    unsigned p = staging[e];
    int slot = atomicAdd(&cursor[p >> 24], 1);
    col[slot] = (int)(p & 0x00FFFFFFu);
  }
  // deferred S *= dinv for rows [node0, node0+nNodes): 12 floats = 3 float4/row
  float4* Sp4 = (float4*)(S + (size_t)node0 * 12);
  int lim = nNodes * 3;
  for (int i = t; i < lim; i += 256) {
    float4 vv = Sp4[i];
    float d = dsh[i / 3];
    vv.x *= d; vv.y *= d; vv.z *= d; vv.w *= d;
    Sp4[i] = vv;
  }
}

// ---------------- Fused weight chain (round-4 proven, byte-identical) -----------
__global__ __launch_bounds__(1024) void k_chain(const float* __restrict__ W_in,
                                                const float* __restrict__ b_in,
                                                const float* __restrict__ W_hid,
                                                const float* __restrict__ b_hid,
                                                const float* __restrict__ W_out,
                                                float* __restrict__ cvec,
                                                float* __restrict__ Y12) {
  __shared__ float Ws[128][132];
  __shared__ float Bt0[16][132];
  __shared__ float Bt1[16][132];
  __shared__ float part[16][17];  // [k-slice][o]
  int t = threadIdx.x;
  for (int i = t; i < 2048; i += 1024) {
    int o = i >> 7, k = i & 127;
    Bt0[o][k] = (o < 10) ? W_out[k * 10 + o] : 0.f;
  }
  float (*Bc)[132] = Bt0;
  float (*Bn)[132] = Bt1;
  const float* Wp[4] = {W_hid + 2 * 16384, W_hid + 16384, W_hid, W_in};
  const float* bp[4] = {b_hid + 256, b_hid + 128, b_hid, b_in};
#pragma unroll 1
  for (int s = 0; s < 4; s++) {
    const float* W = Wp[s];
    __syncthreads();  // Bc ready; Ws free
    for (int i = t; i < 4096; i += 1024) {
      float4 v = ((const float4*)W)[i];
      int r = i >> 5, c4 = i & 31;
      *(float4*)&Ws[r][c4 * 4] = v;
    }
    if (t < 256) {  // bias partials (reads Bc, unaffected by Ws staging)
      int o = t & 15, sl = t >> 4;
      const float* bias = bp[s];
      float a = 0.f;
#pragma unroll
      for (int kk = 0; kk < 8; kk++) {
        int k = sl * 8 + kk;
        a += bias[k] * Bc[o][k];
      }
      part[sl][o] = a;
    }
    __syncthreads();  // Ws + part ready
    for (int i = t; i < 2048; i += 1024) {
      int o = i & 15, r = i >> 4;
      const float4* wr = (const float4*)&Ws[r][0];
      const float4* br = (const float4*)&Bc[o][0];
      float acc = 0.f;
#pragma unroll 8
      for (int k4 = 0; k4 < 32; k4++) {
        float4 w = wr[k4], bb = br[k4];
        acc += w.x * bb.x + w.y * bb.y + w.z * bb.z + w.w * bb.w;
      }
      Bn[o][r] = acc;
    }
    if (t < 16) {
      float a = 0.f;
#pragma unroll
      for (int sl = 0; sl < 16; sl++) a += part[sl][t];
      cvec[(48 - 16 * s) + t] = a;
    }
    { float (*tmp)[132] = Bc; Bc = Bn; Bn = tmp; }
  }
  __syncthreads();
  for (int i = t; i < 2048; i += 1024) {
    int o = i >> 7, k = i & 127;
    if (o < 12) Y12[k * 12 + o] = Bc[o][k];
  }
}

// ---------------- Aggregation: software-pipelined col stream ----------------
// Per 8-edge iteration the R12 loop serialized Lcol + Lstate (col quad load,
// THEN 8 dependent gathers). Here iteration k+1's col quads are issued BEFORE
// iteration k's gathers, overlapping the two latencies. Grid-limited occupancy
// (18 waves/CU) means shorter dependent chains translate directly to time.
__global__ __launch_bounds__(256) void k_agg10(const float4* __restrict__ Sin4,
                                               const int* __restrict__ col,
                                               const int* __restrict__ roff,
                                               const float* __restrict__ dinv,
                                               const float* __restrict__ cvec,
                                               float4* __restrict__ Sout4, int N, int last) {
  int g = blockIdx.x * 256 + threadIdx.x;
  if (g >= N * 3) return;
  int node = g / 3;
  int o = g - node * 3;
  float4 z = Sin4[(size_t)node * 3 + o];
  float ax = z.x, ay = z.y, az = z.z, aw = z.w;
  int j = roff[node], e = roff[node + 1];
  if (j + 7 < e) {
    i4u c0 = *(const i4u*)(col + j);
    i4u c1 = *(const i4u*)(col + j + 4);
    while (true) {
      int jn = j + 8;
      bool more = (jn + 7 < e);
      i4u n0, n1;
      if (more) {  // prefetch next col quads BEFORE the dependent gathers
        n0 = *(const i4u*)(col + jn);
        n1 = *(const i4u*)(col + jn + 4);
      }
      float4 v0 = Sin4[(size_t)c0.x * 3 + o];
      float4 v1 = Sin4[(size_t)c0.y * 3 + o];
      float4 v2 = Sin4[(size_t)c0.z * 3 + o];
      float4 v3 = Sin4[(size_t)c0.w * 3 + o];
      float4 v4 = Sin4[(size_t)c1.x * 3 + o];
      float4 v5 = Sin4[(size_t)c1.y * 3 + o];
      float4 v6 = Sin4[(size_t)c1.z * 3 + o];
      float4 v7 = Sin4[(size_t)c1.w * 3 + o];
      ax += (v0.x + v1.x) + (v2.x + v3.x) + (v4.x + v5.x) + (v6.x + v7.x);
      ay += (v0.y + v1.y) + (v2.y + v3.y) + (v4.y + v5.y) + (v6.y + v7.y);
      az += (v0.z + v1.z) + (v2.z + v3.z) + (v4.z + v5.z) + (v6.z + v7.z);
      aw += (v0.w + v1.w) + (v2.w + v3.w) + (v4.w + v5.w) + (v6.w + v7.w);
      j = jn;
      if (!more) break;
      c0 = n0; c1 = n1;
    }
  }
  for (; j + 3 < e; j += 4) {
    i4u c = *(const i4u*)(col + j);
    float4 v0 = Sin4[(size_t)c.x * 3 + o];
    float4 v1 = Sin4[(size_t)c.y * 3 + o];
    float4 v2 = Sin4[(size_t)c.z * 3 + o];
    float4 v3 = Sin4[(size_t)c.w * 3 + o];
    ax += (v0.x + v1.x) + (v2.x + v3.x);
    ay += (v0.y + v1.y) + (v2.y + v3.y);
    az += (v0.z + v1.z) + (v2.z + v3.z);
    aw += (v0.w + v1.w) + (v2.w + v3.w);
  }
  for (; j < e; j++) {
    float4 v0 = Sin4[(size_t)col[j] * 3 + o];
    ax += v0.x; ay += v0.y; az += v0.z; aw += v0.w;
  }
  float di = dinv[node];
  float sg = last ? di : di * di;
  float sc = last ? 1.f : di;
  float4 cv = ((const float4*)cvec)[o];
  Sout4[(size_t)node * 3 + o] =
      make_float4(sg * ax + sc * cv.x, sg * ay + sc * cv.y,
                  sg * az + sc * cv.z, sg * aw + sc * cv.w);
}

// ---------------- Pooling + bias (gbounds inlined) ----------------

__global__ __launch_bounds__(128) void k_pool(const float* __restrict__ Z,
                                              const int* __restrict__ batch,
                                              const float* __restrict__ b_out,
                                              float* __restrict__ out, int N, int G) {
  __shared__ float red[8][16];
  __shared__ int bounds[2];
  int g = blockIdx.x;
  int t = threadIdx.x;
  if (t < 2) {
    int target = g + t;
    int lo = 0, hi = N;
    while (lo < hi) {
      int mid = (lo + hi) >> 1;
      if (batch[mid] < target) lo = mid + 1; else hi = mid;
    }
    bounds[t] = lo;
  }
  __syncthreads();
  int s = bounds[0], e = bounds[1];
  int f = t & 15, c = t >> 4;
  float acc = 0.f;
  if (f < 10) {
    for (int n = s + c; n < e; n += 8) acc += Z[(size_t)n * 12 + f];
  }
  red[c][f] = acc;
  __syncthreads();
  if (c == 0 && f < 10) {
    float a = 0.f;
#pragma unroll
    for (int i = 0; i < 8; i++) a += red[i][f];
    out[g * 10 + f] = a / fmaxf((float)(e - s), 1.f) + b_out[f];
  }
}

// ---------------- launch ----------------

extern "C" void kernel_launch(void* const* d_in, const int* in_sizes, int n_in,
                              void* d_out, int out_size, void* d_ws, size_t ws_size,
                              hipStream_t stream) {
  const float* x     = (const float*)d_in[0];
  const int*   eidx  = (const int*)d_in[1];
  const int*   batch = (const int*)d_in[2];
  const float* W_in  = (const float*)d_in[3];
  const float* b_in  = (const float*)d_in[4];
  const float* W_hid = (const float*)d_in[5];
  const float* b_hid = (const float*)d_in[6];
  const float* W_out = (const float*)d_in[7];
  const float* b_out = (const float*)d_in[8];

  const int N = in_sizes[0] / 128;
  const int E = in_sizes[1] / 2;
  const int G = out_size / 10;

  const int* src = eidx;
  const int* dst = eidx + E;

  const int NB = (N + 255) >> BK_SHIFT;
  const int NBLK = (E + CHUNK - 1) / CHUNK;
  const int XYB = (N + 127) / 128;

  char* ws = (char*)d_ws;
  size_t off = 0;
  auto alloc = [&](size_t b) {
    char* p = ws + off;
    off = (off + b + 255) & ~(size_t)255;
    return p;
  };
  unsigned* staging = (unsigned*)alloc((size_t)E * 4);
  int*   col     = (int*)alloc((size_t)E * 4 + 16);
  int*   blkcnt  = (int*)alloc((size_t)NB * NBLK * 4);
  int*   btot    = (int*)alloc((size_t)NB * 4);
  int*   bbase   = (int*)alloc((size_t)(NB + 1) * 4);
  int*   roff    = (int*)alloc((size_t)(N + 1) * 4);
  float* dinv    = (float*)alloc((size_t)N * 4);
  float* stateA  = (float*)alloc((size_t)N * 12 * 4);
  float* stateB  = (float*)alloc((size_t)N * 12 * 4);
  float* Y12     = (float*)alloc(128 * 12 * 4);
  float* cvec    = (float*)alloc(4 * 16 * 4);
  (void)ws_size; (void)n_in;

  // Weight chain (single kernel, 1024 thr, parallel bias reduce)
  k_chain<<<1, 1024, 0, stream>>>(W_in, b_in, W_hid, b_hid, W_out, cvec, Y12);

  // Bucketed CSR build; xy (unscaled) merged into the scatter dispatch
  k_bucket_count<<<NBLK, 256, 0, stream>>>(dst, blkcnt, E, NB, NBLK);
  k_bucket_scanB<<<NB, 512, 0, stream>>>(blkcnt, btot, NBLK);
  k_bucket_base<<<1, 1024, 0, stream>>>(btot, bbase, NB);
  k_scatter_xy<<<NBLK + XYB, 256, 0, stream>>>(src, dst, blkcnt, bbase, staging,
                                               E, NB, NBLK, x, Y12, stateA, N);
  k_csr_build<<<NB, 256, 0, stream>>>(staging, bbase, roff, dinv, col, stateA, N, NB, E);

  // 4 gather passes (3N threads, software-pipelined col stream)
  float* zi = stateA;
  float* zo = stateB;
  int aggBlocks = (N * 3 + 255) / 256;
  for (int l = 0; l < 4; l++) {
    k_agg10<<<aggBlocks, 256, 0, stream>>>((const float4*)zi, col, roff, dinv,
                                           cvec + 16 * l, (float4*)zo, N, (l == 3) ? 1 : 0);
    float* t = zi; zi = zo; zo = t;
  }

  k_pool<<<G, 128, 0, stream>>>(zi, batch, b_out, (float*)d_out, N, G);
}

// Round 14
// 260.716 us; speedup vs baseline: 1.1111x; 1.0071x over previous
//
#include <hip/hip_runtime.h>

#define BK_SHIFT 8
#define NB_MAX 512
#define CHUNK 4096

typedef int i4u __attribute__((ext_vector_type(4), aligned(4)));

// ---------------- Pass A: per-block bucket histogram (bucket = dst >> 8) -------
__global__ __launch_bounds__(256) void k_bucket_count(const int* __restrict__ dst,
                                                      int* __restrict__ blkcnt,
                                                      int E, int NB, int NBLK) {
  __shared__ int cnt[NB_MAX];
  int t = threadIdx.x, b = blockIdx.x;
  for (int i = t; i < NB; i += 256) cnt[i] = 0;
  __syncthreads();
  int e0 = b * CHUNK, e1 = min(E, e0 + CHUNK);
  if (e1 - e0 == CHUNK) {
    const int4* d4 = (const int4*)(dst + e0);
#pragma unroll 2
    for (int i = t; i < CHUNK / 4; i += 256) {
      int4 v = d4[i];
      atomicAdd(&cnt[v.x >> BK_SHIFT], 1);
      atomicAdd(&cnt[v.y >> BK_SHIFT], 1);
      atomicAdd(&cnt[v.z >> BK_SHIFT], 1);
      atomicAdd(&cnt[v.w >> BK_SHIFT], 1);
    }
  } else {
    for (int e = e0 + t; e < e1; e += 256) atomicAdd(&cnt[dst[e] >> BK_SHIFT], 1);
  }
  __syncthreads();
  for (int i = t; i < NB; i += 256) blkcnt[(size_t)i * NBLK + b] = cnt[i];
}

// Pass B: per-bucket exclusive scan across blocks (in place), bucket totals out.
__global__ __launch_bounds__(512) void k_bucket_scanB(int* __restrict__ blkcnt,
                                                      int* __restrict__ btot, int NBLK) {
  __shared__ int v[512];
  int t = threadIdx.x, k = blockIdx.x;
  int x = (t < NBLK) ? blkcnt[(size_t)k * NBLK + t] : 0;
  v[t] = x;
  __syncthreads();
  for (int off = 1; off < 512; off <<= 1) {
    int u = (t >= off) ? v[t - off] : 0;
    __syncthreads();
    v[t] += u;
    __syncthreads();
  }
  if (t < NBLK) blkcnt[(size_t)k * NBLK + t] = v[t] - x;  // exclusive
  if (t == 511) btot[k] = v[511];
}

// Pass B2: exclusive scan over bucket totals -> bucket base offsets
__global__ __launch_bounds__(1024) void k_bucket_base(const int* __restrict__ btot,
                                                      int* __restrict__ bbase, int NB) {
  __shared__ int v[1024];
  int t = threadIdx.x;
  int x = (t < NB) ? btot[t] : 0;
  v[t] = x;
  __syncthreads();
  for (int off = 1; off < 1024; off <<= 1) {
    int u = (t >= off) ? v[t - off] : 0;
    __syncthreads();
    v[t] += u;
    __syncthreads();
  }
  if (t < NB) bbase[t] = v[t] - x;
  if (t == 1023) bbase[NB] = v[1023];
}

// ---------------- Merged scatter + xy (one dispatch) ----------------
// Scatter blocks [0, NBLK): DIRECT-WRITE scatter. The old LDS-sort staged
// sval/ga0 in LDS, requiring a per-block histogram + 16-barrier scan purely
// to pack LDS slots -- but blkoff/bbase (from count+scanB+base) already give
// the exact global run offset gofs[bk] = bbase[bk] + blkoff[bk][b]. Writing
// staging[gofs[bk] + atomicAdd(curs[bk],1)] directly keeps the same dense
// runs (order within a run changes only), deletes the histogram, the scan,
// both LDS staging arrays (39KB -> 4KB) and ~17 barriers. All 391 blocks are
// co-resident, so kernel time == block critical path -- which this collapses.
// Blocks [NBLK, NBLK+XYB): S_raw = X @ Y12 (unscaled; dinv in k_csr_build).
// staging word = (d & 255) << 24 | src
__global__ __launch_bounds__(256) void k_scatter_xy(const int* __restrict__ src,
                                                    const int* __restrict__ dst,
                                                    const int* __restrict__ blkoff,
                                                    const int* __restrict__ bbase,
                                                    unsigned* __restrict__ staging,
                                                    int E, int NB, int NBLK,
                                                    const float* __restrict__ X,
                                                    const float* __restrict__ Y12,
                                                    float* __restrict__ S, int N) {
  __shared__ float smem[19008];  // xy: Xs[128][132]+Yt[16][132]=76KB; scatter: 4KB
  int t = threadIdx.x, b = blockIdx.x;

  if (b < NBLK) {
    int* gofs = (int*)smem;          // [0, 512)
    int* curs = (int*)smem + 512;    // [512, 1024)
    for (int i = t; i < NB; i += 256) {
      gofs[i] = bbase[i] + blkoff[(size_t)i * NBLK + b];
      curs[i] = 0;
    }
    __syncthreads();
    int e0 = b * CHUNK, e1 = min(E, e0 + CHUNK);
    if (e1 - e0 == CHUNK) {
      const int4* d4 = (const int4*)(dst + e0);
      const int4* s4 = (const int4*)(src + e0);
#pragma unroll 2
      for (int i = t; i < CHUNK / 4; i += 256) {
        int4 d = d4[i];
        int4 s = s4[i];
        int b0 = d.x >> BK_SHIFT, b1 = d.y >> BK_SHIFT;
        int b2 = d.z >> BK_SHIFT, b3 = d.w >> BK_SHIFT;
        int s0 = atomicAdd(&curs[b0], 1);
        int s1 = atomicAdd(&curs[b1], 1);
        int s2 = atomicAdd(&curs[b2], 1);
        int s3 = atomicAdd(&curs[b3], 1);
        staging[gofs[b0] + s0] = ((unsigned)(d.x & 255) << 24) | (unsigned)s.x;
        staging[gofs[b1] + s1] = ((unsigned)(d.y & 255) << 24) | (unsigned)s.y;
        staging[gofs[b2] + s2] = ((unsigned)(d.z & 255) << 24) | (unsigned)s.z;
        staging[gofs[b3] + s3] = ((unsigned)(d.w & 255) << 24) | (unsigned)s.w;
      }
    } else {
      for (int e = e0 + t; e < e1; e += 256) {
        int d = dst[e];
        int bk = d >> BK_SHIFT;
        int slot = atomicAdd(&curs[bk], 1);
        staging[gofs[bk] + slot] = ((unsigned)(d & 255) << 24) | (unsigned)src[e];
      }
    }
    return;
  }

  // ---- xy path: S_raw = X @ Y12 (unscaled) ----
  float (*Xs)[132] = (float(*)[132])smem;            // 128 x 132
  float (*Yt)[132] = (float(*)[132])(smem + 16896);  // 16 x 132
  int n0 = (b - NBLK) * 128;
  for (int i = t; i < 2048; i += 256) {
    int k = i >> 4, o = i & 15;
    Yt[o][k] = (o < 12) ? Y12[k * 12 + o] : 0.f;
  }
#pragma unroll
  for (int it = 0; it < 16; it++) {
    int idx = t + it * 256;
    int r = idx >> 5;
    int c4 = idx & 31;
    int row = n0 + r;
    float4 vv = *(const float4*)&X[(size_t)(row < N ? row : 0) * 128 + c4 * 4];
    *(float4*)&Xs[r][c4 * 4] = vv;
  }
  __syncthreads();
  int cp = t & 7;
  int q = t >> 3;
  float acc[4][2];
#pragma unroll
  for (int i = 0; i < 4; i++) { acc[i][0] = 0.f; acc[i][1] = 0.f; }
  const float4* y0r = (const float4*)&Yt[2 * cp][0];
  const float4* y1r = (const float4*)&Yt[2 * cp + 1][0];
#pragma unroll 4
  for (int k4 = 0; k4 < 32; k4++) {
    float4 y0 = y0r[k4];
    float4 y1 = y1r[k4];
#pragma unroll
    for (int i = 0; i < 4; i++) {
      float4 xv = *(const float4*)&Xs[q + 32 * i][k4 * 4];
      acc[i][0] += xv.x * y0.x + xv.y * y0.y + xv.z * y0.z + xv.w * y0.w;
      acc[i][1] += xv.x * y1.x + xv.y * y1.y + xv.z * y1.z + xv.w * y1.w;
    }
  }
#pragma unroll
  for (int i = 0; i < 4; i++) {
    int node = n0 + q + 32 * i;
    if (node < N && cp < 6) {
      *(float2*)&S[(size_t)node * 12 + 2 * cp] = make_float2(acc[i][0], acc[i][1]);
    }
  }
}

// Pass D: counts -> dinv + roff, in-bucket col scatter, deferred S *= dinv.
__global__ __launch_bounds__(256) void k_csr_build(const unsigned* __restrict__ staging,
                                                   const int* __restrict__ bbase,
                                                   int* __restrict__ roff,
                                                   float* __restrict__ dinv,
                                                   int* __restrict__ col,
                                                   float* __restrict__ S,
                                                   int N, int NB, int E) {
  __shared__ int cnt[256];
  __shared__ int sa[256], sb[256];
  __shared__ int cursor[256];
  __shared__ float dsh[256];
  int t = threadIdx.x, k = blockIdx.x;
  int node0 = k << BK_SHIFT;
  int nNodes = min(256, N - node0);
  int e0 = bbase[k], e1 = bbase[k + 1];
  cnt[t] = 0;
  __syncthreads();
  for (int e = e0 + t; e < e1; e += 256) atomicAdd(&cnt[staging[e] >> 24], 1);
  __syncthreads();
  int* a = sa;
  int* bq = sb;
  a[t] = cnt[t];
  __syncthreads();
  for (int off = 1; off < 256; off <<= 1) {
    bq[t] = (t >= off) ? a[t] + a[t - off] : a[t];
    __syncthreads();
    int* tmp = a; a = bq; bq = tmp;
  }
  {
    int excl = e0 + ((t > 0) ? a[t - 1] : 0);
    cursor[t] = excl;
    float di = rsqrtf((float)(cnt[t] + 1));  // +1 = self loop
    dsh[t] = di;
    if (t < nNodes) {
      roff[node0 + t] = excl;
      dinv[node0 + t] = di;
    }
  }
  if (k == NB - 1 && t == 0) roff[N] = E;
  __syncthreads();
  for (int e = e0 + t; e < e1; e += 256) {
    unsigned p = staging[e];
    int slot = atomicAdd(&cursor[p >> 24], 1);
    col[slot] = (int)(p & 0x00FFFFFFu);
  }
  // deferred S *= dinv for rows [node0, node0+nNodes): 12 floats = 3 float4/row
  float4* Sp4 = (float4*)(S + (size_t)node0 * 12);
  int lim = nNodes * 3;
  for (int i = t; i < lim; i += 256) {
    float4 vv = Sp4[i];
    float d = dsh[i / 3];
    vv.x *= d; vv.y *= d; vv.z *= d; vv.w *= d;
    Sp4[i] = vv;
  }
}

// ---------------- Fused weight chain (round-4 proven, byte-identical) -----------
__global__ __launch_bounds__(1024) void k_chain(const float* __restrict__ W_in,
                                                const float* __restrict__ b_in,
                                                const float* __restrict__ W_hid,
                                                const float* __restrict__ b_hid,
                                                const float* __restrict__ W_out,
                                                float* __restrict__ cvec,
                                                float* __restrict__ Y12) {
  __shared__ float Ws[128][132];
  __shared__ float Bt0[16][132];
  __shared__ float Bt1[16][132];
  __shared__ float part[16][17];  // [k-slice][o]
  int t = threadIdx.x;
  for (int i = t; i < 2048; i += 1024) {
    int o = i >> 7, k = i & 127;
    Bt0[o][k] = (o < 10) ? W_out[k * 10 + o] : 0.f;
  }
  float (*Bc)[132] = Bt0;
  float (*Bn)[132] = Bt1;
  const float* Wp[4] = {W_hid + 2 * 16384, W_hid + 16384, W_hid, W_in};
  const float* bp[4] = {b_hid + 256, b_hid + 128, b_hid, b_in};
#pragma unroll 1
  for (int s = 0; s < 4; s++) {
    const float* W = Wp[s];
    __syncthreads();  // Bc ready; Ws free
    for (int i = t; i < 4096; i += 1024) {
      float4 v = ((const float4*)W)[i];
      int r = i >> 5, c4 = i & 31;
      *(float4*)&Ws[r][c4 * 4] = v;
    }
    if (t < 256) {  // bias partials (reads Bc, unaffected by Ws staging)
      int o = t & 15, sl = t >> 4;
      const float* bias = bp[s];
      float a = 0.f;
#pragma unroll
      for (int kk = 0; kk < 8; kk++) {
        int k = sl * 8 + kk;
        a += bias[k] * Bc[o][k];
      }
      part[sl][o] = a;
    }
    __syncthreads();  // Ws + part ready
    for (int i = t; i < 2048; i += 1024) {
      int o = i & 15, r = i >> 4;
      const float4* wr = (const float4*)&Ws[r][0];
      const float4* br = (const float4*)&Bc[o][0];
      float acc = 0.f;
#pragma unroll 8
      for (int k4 = 0; k4 < 32; k4++) {
        float4 w = wr[k4], bb = br[k4];
        acc += w.x * bb.x + w.y * bb.y + w.z * bb.z + w.w * bb.w;
      }
      Bn[o][r] = acc;
    }
    if (t < 16) {
      float a = 0.f;
#pragma unroll
      for (int sl = 0; sl < 16; sl++) a += part[sl][t];
      cvec[(48 - 16 * s) + t] = a;
    }
    { float (*tmp)[132] = Bc; Bc = Bn; Bn = tmp; }
  }
  __syncthreads();
  for (int i = t; i < 2048; i += 1024) {
    int o = i >> 7, k = i & 127;
    if (o < 12) Y12[k * 12 + o] = Bc[o][k];
  }
}

// ---------------- Aggregation (R13 proven: col-prefetch pipeline) ----------------
__global__ __launch_bounds__(256) void k_agg10(const float4* __restrict__ Sin4,
                                               const int* __restrict__ col,
                                               const int* __restrict__ roff,
                                               const float* __restrict__ dinv,
                                               const float* __restrict__ cvec,
                                               float4* __restrict__ Sout4, int N, int last) {
  int g = blockIdx.x * 256 + threadIdx.x;
  if (g >= N * 3) return;
  int node = g / 3;
  int o = g - node * 3;
  float4 z = Sin4[(size_t)node * 3 + o];
  float ax = z.x, ay = z.y, az = z.z, aw = z.w;
  int j = roff[node], e = roff[node + 1];
  if (j + 7 < e) {
    i4u c0 = *(const i4u*)(col + j);
    i4u c1 = *(const i4u*)(col + j + 4);
    while (true) {
      int jn = j + 8;
      bool more = (jn + 7 < e);
      i4u n0, n1;
      if (more) {  // prefetch next col quads BEFORE the dependent gathers
        n0 = *(const i4u*)(col + jn);
        n1 = *(const i4u*)(col + jn + 4);
      }
      float4 v0 = Sin4[(size_t)c0.x * 3 + o];
      float4 v1 = Sin4[(size_t)c0.y * 3 + o];
      float4 v2 = Sin4[(size_t)c0.z * 3 + o];
      float4 v3 = Sin4[(size_t)c0.w * 3 + o];
      float4 v4 = Sin4[(size_t)c1.x * 3 + o];
      float4 v5 = Sin4[(size_t)c1.y * 3 + o];
      float4 v6 = Sin4[(size_t)c1.z * 3 + o];
      float4 v7 = Sin4[(size_t)c1.w * 3 + o];
      ax += (v0.x + v1.x) + (v2.x + v3.x) + (v4.x + v5.x) + (v6.x + v7.x);
      ay += (v0.y + v1.y) + (v2.y + v3.y) + (v4.y + v5.y) + (v6.y + v7.y);
      az += (v0.z + v1.z) + (v2.z + v3.z) + (v4.z + v5.z) + (v6.z + v7.z);
      aw += (v0.w + v1.w) + (v2.w + v3.w) + (v4.w + v5.w) + (v6.w + v7.w);
      j = jn;
      if (!more) break;
      c0 = n0; c1 = n1;
    }
  }
  for (; j + 3 < e; j += 4) {
    i4u c = *(const i4u*)(col + j);
    float4 v0 = Sin4[(size_t)c.x * 3 + o];
    float4 v1 = Sin4[(size_t)c.y * 3 + o];
    float4 v2 = Sin4[(size_t)c.z * 3 + o];
    float4 v3 = Sin4[(size_t)c.w * 3 + o];
    ax += (v0.x + v1.x) + (v2.x + v3.x);
    ay += (v0.y + v1.y) + (v2.y + v3.y);
    az += (v0.z + v1.z) + (v2.z + v3.z);
    aw += (v0.w + v1.w) + (v2.w + v3.w);
  }
  for (; j < e; j++) {
    float4 v0 = Sin4[(size_t)col[j] * 3 + o];
    ax += v0.x; ay += v0.y; az += v0.z; aw += v0.w;
  }
  float di = dinv[node];
  float sg = last ? di : di * di;
  float sc = last ? 1.f : di;
  float4 cv = ((const float4*)cvec)[o];
  Sout4[(size_t)node * 3 + o] =
      make_float4(sg * ax + sc * cv.x, sg * ay + sc * cv.y,
                  sg * az + sc * cv.z, sg * aw + sc * cv.w);
}

// ---------------- Pooling + bias (gbounds inlined) ----------------

__global__ __launch_bounds__(128) void k_pool(const float* __restrict__ Z,
                                              const int* __restrict__ batch,
                                              const float* __restrict__ b_out,
                                              float* __restrict__ out, int N, int G) {
  __shared__ float red[8][16];
  __shared__ int bounds[2];
  int g = blockIdx.x;
  int t = threadIdx.x;
  if (t < 2) {
    int target = g + t;
    int lo = 0, hi = N;
    while (lo < hi) {
      int mid = (lo + hi) >> 1;
      if (batch[mid] < target) lo = mid + 1; else hi = mid;
    }
    bounds[t] = lo;
  }
  __syncthreads();
  int s = bounds[0], e = bounds[1];
  int f = t & 15, c = t >> 4;
  float acc = 0.f;
  if (f < 10) {
    for (int n = s + c; n < e; n += 8) acc += Z[(size_t)n * 12 + f];
  }
  red[c][f] = acc;
  __syncthreads();
  if (c == 0 && f < 10) {
    float a = 0.f;
#pragma unroll
    for (int i = 0; i < 8; i++) a += red[i][f];
    out[g * 10 + f] = a / fmaxf((float)(e - s), 1.f) + b_out[f];
  }
}

// ---------------- launch ----------------

extern "C" void kernel_launch(void* const* d_in, const int* in_sizes, int n_in,
                              void* d_out, int out_size, void* d_ws, size_t ws_size,
                              hipStream_t stream) {
  const float* x     = (const float*)d_in[0];
  const int*   eidx  = (const int*)d_in[1];
  const int*   batch = (const int*)d_in[2];
  const float* W_in  = (const float*)d_in[3];
  const float* b_in  = (const float*)d_in[4];
  const float* W_hid = (const float*)d_in[5];
  const float* b_hid = (const float*)d_in[6];
  const float* W_out = (const float*)d_in[7];
  const float* b_out = (const float*)d_in[8];

  const int N = in_sizes[0] / 128;
  const int E = in_sizes[1] / 2;
  const int G = out_size / 10;

  const int* src = eidx;
  const int* dst = eidx + E;

  const int NB = (N + 255) >> BK_SHIFT;
  const int NBLK = (E + CHUNK - 1) / CHUNK;
  const int XYB = (N + 127) / 128;

  char* ws = (char*)d_ws;
  size_t off = 0;
  auto alloc = [&](size_t b) {
    char* p = ws + off;
    off = (off + b + 255) & ~(size_t)255;
    return p;
  };
  unsigned* staging = (unsigned*)alloc((size_t)E * 4);
  int*   col     = (int*)alloc((size_t)E * 4 + 16);
  int*   blkcnt  = (int*)alloc((size_t)NB * NBLK * 4);
  int*   btot    = (int*)alloc((size_t)NB * 4);
  int*   bbase   = (int*)alloc((size_t)(NB + 1) * 4);
  int*   roff    = (int*)alloc((size_t)(N + 1) * 4);
  float* dinv    = (float*)alloc((size_t)N * 4);
  float* stateA  = (float*)alloc((size_t)N * 12 * 4);
  float* stateB  = (float*)alloc((size_t)N * 12 * 4);
  float* Y12     = (float*)alloc(128 * 12 * 4);
  float* cvec    = (float*)alloc(4 * 16 * 4);
  (void)ws_size; (void)n_in;

  // Weight chain (single kernel, 1024 thr, parallel bias reduce)
  k_chain<<<1, 1024, 0, stream>>>(W_in, b_in, W_hid, b_hid, W_out, cvec, Y12);

  // Bucketed CSR build; direct-write scatter + xy merged in one dispatch
  k_bucket_count<<<NBLK, 256, 0, stream>>>(dst, blkcnt, E, NB, NBLK);
  k_bucket_scanB<<<NB, 512, 0, stream>>>(blkcnt, btot, NBLK);
  k_bucket_base<<<1, 1024, 0, stream>>>(btot, bbase, NB);
  k_scatter_xy<<<NBLK + XYB, 256, 0, stream>>>(src, dst, blkcnt, bbase, staging,
                                               E, NB, NBLK, x, Y12, stateA, N);
  k_csr_build<<<NB, 256, 0, stream>>>(staging, bbase, roff, dinv, col, stateA, N, NB, E);

  // 4 gather passes (3N threads, software-pipelined col stream)
  float* zi = stateA;
  float* zo = stateB;
  int aggBlocks = (N * 3 + 255) / 256;
  for (int l = 0; l < 4; l++) {
    k_agg10<<<aggBlocks, 256, 0, stream>>>((const float4*)zi, col, roff, dinv,
                                           cvec + 16 * l, (float4*)zo, N, (l == 3) ? 1 : 0);
    float* t = zi; zi = zo; zo = t;
  }

  k_pool<<<G, 128, 0, stream>>>(zi, batch, b_out, (float*)d_out, N, G);
}